// Round 4
// baseline (1920.223 us; speedup 1.0000x reference)
//
#include <hip/hip_runtime.h>
#include <hip/hip_bf16.h>

#define NH   16
#define DHD  32
#define SEQ  2048
#define NB   2
#define XROW 1536          // 3*NH*DHD
#define RPB  128           // q rows per block
#define KT   64            // key tile

// present[b][c][h][s][d] = x[b][s][(1+c)*512 + h*32 + d]; fp32 -> fp32 relayout.
__global__ void present_copy(const float* __restrict__ x,
                             float* __restrict__ pres) {
    long o = ((long)blockIdx.x * blockDim.x + threadIdx.x) * 4;  // 4 floats per thread
    int d0 = (int)(o & 31);
    int s  = (int)((o >> 5) & (SEQ - 1));
    int h  = (int)((o >> 16) & (NH - 1));
    int c  = (int)((o >> 20) & 1);
    int b  = (int)(o >> 21);
    const float4* in = (const float4*)(x + ((long)(b * SEQ + s)) * XROW
                                       + (1 + c) * 512 + h * 32 + d0);
    *((float4*)(pres + o)) = in[0];
}

__global__ __launch_bounds__(RPB)
void attn_kernel(const float* __restrict__ x,
                 const float* __restrict__ E,
                 float* __restrict__ out) {
    __shared__ float kt[KT][DHD];
    __shared__ float vt[KT][DHD];

    int bh = blockIdx.x & 31;          // b*16+h
    int rt = 15 - (blockIdx.x >> 5);   // heavy row-tiles dispatched first
    int b  = bh >> 4;
    int h  = bh & 15;
    int tid = threadIdx.x;
    int i  = rt * RPB + tid;           // this thread's q row

    float q[DHD];
    {
        const float4* q4 = (const float4*)(x + ((long)(b * SEQ + i)) * XROW + h * 32);
#pragma unroll
        for (int t = 0; t < 8; ++t) ((float4*)q)[t] = q4[t];
    }

    float m = -1e30f, l = 0.f;
    float acc[DHD];
#pragma unroll
    for (int d = 0; d < DHD; ++d) acc[d] = 0.f;

    // rel score uses E row (S-1-i+j); base at j=0
    const float* ebase = E + ((long)h * SEQ + (SEQ - 1 - i)) * DHD;

    int ntile = (rt + 1) * 2;
    for (int t0 = 0; t0 < ntile; ++t0) {
        int j0 = t0 * KT;
        {   // stage K (threads 0..63) and V (threads 64..127), one row each
            int r = tid & 63;
            int isv = tid >> 6;
            const float4* s4 = (const float4*)(x + ((long)(b * SEQ + j0 + r)) * XROW
                                               + (1 + isv) * 512 + h * 32);
            float4 tmp[8];
#pragma unroll
            for (int t = 0; t < 8; ++t) tmp[t] = s4[t];
            float* dst = isv ? &vt[r][0] : &kt[r][0];
#pragma unroll
            for (int t = 0; t < 8; ++t) ((float4*)dst)[t] = tmp[t];
        }
        __syncthreads();

        int jend = i - j0 + 1;               // causal: j <= i
        if (jend > KT) jend = KT;
        for (int jj = 0; jj < jend; ++jj) {
            float e[DHD];
            const float4* e4 = (const float4*)(ebase + (long)(j0 + jj) * DHD);
#pragma unroll
            for (int t = 0; t < 8; ++t) ((float4*)e)[t] = e4[t];

            float dk = 0.f, de = 0.f;
#pragma unroll
            for (int d = 0; d < DHD; ++d) {
                dk = __builtin_fmaf(q[d], kt[jj][d], dk);
                de = __builtin_fmaf(q[d], e[d], de);
            }
            float sc = (dk + de) * 0.17677669529663687f;  // rsqrt(32)

            if (sc > m) {                     // rare rescale
                float r = __expf(m - sc);
                l *= r;
#pragma unroll
                for (int d = 0; d < DHD; ++d) acc[d] *= r;
                m = sc;
            }
            float p = __expf(sc - m);
            l += p;
#pragma unroll
            for (int d = 0; d < DHD; ++d)
                acc[d] = __builtin_fmaf(p, vt[jj][d], acc[d]);
        }
        __syncthreads();
    }

    float inv = 1.0f / l;
    float* op = out + ((long)(b * SEQ + i)) * 512 + h * 32;
#pragma unroll
    for (int t = 0; t < 8; ++t) {
        float4 w;
        w.x = acc[t * 4 + 0] * inv;
        w.y = acc[t * 4 + 1] * inv;
        w.z = acc[t * 4 + 2] * inv;
        w.w = acc[t * 4 + 3] * inv;
        ((float4*)op)[t] = w;
    }
}

extern "C" void kernel_launch(void* const* d_in, const int* in_sizes, int n_in,
                              void* d_out, int out_size, void* d_ws, size_t ws_size,
                              hipStream_t stream) {
    const float* x = (const float*)d_in[0];
    const float* E = (const float*)d_in[1];
    if (n_in >= 2 && in_sizes[0] == 1048576) {  // defensive: select by size
        const float* t = x; x = E; E = t;
    }
    float* a    = (float*)d_out;
    float* pres = a + (long)NB * SEQ * NH * DHD;   // output 1 after output 0

    attn_kernel<<<dim3(32 * 16), dim3(RPB), 0, stream>>>(x, E, a);
    // 4,194,304 elements / 4 per thread / 256 per block = 4096 blocks
    present_copy<<<dim3(4096), dim3(256), 0, stream>>>(x, pres);
}

// Round 5
// 1135.226 us; speedup vs baseline: 1.6915x; 1.6915x over previous
//
#include <hip/hip_runtime.h>
#include <hip/hip_bf16.h>

#define NH   16
#define DHD  32
#define SEQ  2048
#define NB   2
#define XROW 1536          // 3*NH*DHD
#define RPB  128           // q rows per block
#define KT   64            // key tile
#define EROWS 192          // E window rows per tile (needs 191)
#define EPITCH 33          // +1 pad: per-lane b32 reads conflict-free
#define KVP  36            // kt/vt row pitch: 16B-aligned, breaks staging conflict

// present[b][c][h][s][d] = x[b][s][(1+c)*512 + h*32 + d]; fp32 -> fp32 relayout.
__global__ void present_copy(const float* __restrict__ x,
                             float* __restrict__ pres) {
    long o = ((long)blockIdx.x * blockDim.x + threadIdx.x) * 4;  // 4 floats per thread
    int d0 = (int)(o & 31);
    int s  = (int)((o >> 5) & (SEQ - 1));
    int h  = (int)((o >> 16) & (NH - 1));
    int c  = (int)((o >> 20) & 1);
    int b  = (int)(o >> 21);
    const float4* in = (const float4*)(x + ((long)(b * SEQ + s)) * XROW
                                       + (1 + c) * 512 + h * 32 + d0);
    *((float4*)(pres + o)) = in[0];
}

__global__ __launch_bounds__(RPB)
void attn_kernel(const float* __restrict__ x,
                 const float* __restrict__ E,
                 float* __restrict__ out) {
    __shared__ float kt[KT][KVP];
    __shared__ float vt[KT][KVP];
    __shared__ float et[EROWS][EPITCH];

    int bh = blockIdx.x & 31;          // b*16+h
    int rt = 15 - (blockIdx.x >> 5);   // heavy row-tiles dispatched first
    int b  = bh >> 4;
    int h  = bh & 15;
    int tid = threadIdx.x;
    int r0 = rt * RPB;
    int i  = r0 + tid;                 // this thread's q row

    float q[DHD];
    {
        const float4* q4 = (const float4*)(x + ((long)(b * SEQ + i)) * XROW + h * 32);
#pragma unroll
        for (int t = 0; t < 8; ++t) ((float4*)q)[t] = q4[t];
    }

    float m = -1e30f, l = 0.f;
    float acc[DHD];
#pragma unroll
    for (int d = 0; d < DHD; ++d) acc[d] = 0.f;

    const float* Eh = E + (long)h * SEQ * DHD;  // head's E table

    int ntile = (rt + 1) * 2;
    for (int t0 = 0; t0 < ntile; ++t0) {
        int j0 = t0 * KT;
        {   // stage K (threads 0..63) and V (threads 64..127), one row each
            int r = tid & 63;
            int isv = tid >> 6;
            const float4* s4 = (const float4*)(x + ((long)(b * SEQ + j0 + r)) * XROW
                                               + (1 + isv) * 512 + h * 32);
            float4 tmp[8];
#pragma unroll
            for (int t = 0; t < 8; ++t) tmp[t] = s4[t];
            float* dst = isv ? &vt[r][0] : &kt[r][0];
#pragma unroll
            for (int t = 0; t < 8; ++t) ((float4*)dst)[t] = tmp[t];
        }
        {   // stage E window: rows eb0 .. eb0+191 (in-tile row = 127 - tid + jj)
            int eb0 = (SEQ - 1) - (r0 + RPB - 1) + j0;   // = 1920 - r0 + j0
#pragma unroll
            for (int p = 0; p < 12; ++p) {
                int idx = p * RPB + tid;                 // 0..1535
                int r  = idx >> 3;                       // E window row
                int q4 = idx & 7;                        // float4 slot in row
                int gr = eb0 + r; if (gr > SEQ - 1) gr = SEQ - 1;  // clamp (masked rows)
                float4 g = *(const float4*)(Eh + (long)gr * DHD + q4 * 4);
                et[r][q4 * 4 + 0] = g.x;
                et[r][q4 * 4 + 1] = g.y;
                et[r][q4 * 4 + 2] = g.z;
                et[r][q4 * 4 + 3] = g.w;
            }
        }
        __syncthreads();

        int jend = i - j0 + 1;               // causal: j <= i
        if (jend > KT) jend = KT;
        int er0 = RPB - 1 - tid;             // E window row at jj=0
        for (int jj = 0; jj < jend; ++jj) {
            const float* ep = &et[er0 + jj][0];
            float dk = 0.f, de = 0.f;
#pragma unroll
            for (int d = 0; d < DHD; ++d) {
                dk = __builtin_fmaf(q[d], kt[jj][d], dk);
                de = __builtin_fmaf(q[d], ep[d], de);
            }
            float sc = (dk + de) * 0.17677669529663687f;  // rsqrt(32)

            if (sc > m) {                     // rare rescale
                float r = __expf(m - sc);
                l *= r;
#pragma unroll
                for (int d = 0; d < DHD; ++d) acc[d] *= r;
                m = sc;
            }
            float p = __expf(sc - m);
            l += p;
#pragma unroll
            for (int d = 0; d < DHD; ++d)
                acc[d] = __builtin_fmaf(p, vt[jj][d], acc[d]);
        }
        __syncthreads();
    }

    float inv = 1.0f / l;
    float* op = out + ((long)(b * SEQ + i)) * 512 + h * 32;
#pragma unroll
    for (int t = 0; t < 8; ++t) {
        float4 w;
        w.x = acc[t * 4 + 0] * inv;
        w.y = acc[t * 4 + 1] * inv;
        w.z = acc[t * 4 + 2] * inv;
        w.w = acc[t * 4 + 3] * inv;
        ((float4*)op)[t] = w;
    }
}

extern "C" void kernel_launch(void* const* d_in, const int* in_sizes, int n_in,
                              void* d_out, int out_size, void* d_ws, size_t ws_size,
                              hipStream_t stream) {
    const float* x = (const float*)d_in[0];
    const float* E = (const float*)d_in[1];
    if (n_in >= 2 && in_sizes[0] == 1048576) {  // defensive: select by size
        const float* t = x; x = E; E = t;
    }
    float* a    = (float*)d_out;
    float* pres = a + (long)NB * SEQ * NH * DHD;   // output 1 after output 0

    attn_kernel<<<dim3(32 * 16), dim3(RPB), 0, stream>>>(x, E, a);
    present_copy<<<dim3(4096), dim3(256), 0, stream>>>(x, pres);
}

// Round 6
// 549.490 us; speedup vs baseline: 3.4946x; 2.0660x over previous
//
#include <hip/hip_runtime.h>
#include <hip/hip_bf16.h>

#define NH   16
#define DHD  32
#define SEQ  2048
#define NB   2
#define XROW 1536          // 3*NH*DHD
#define RPB  128           // q rows per block
#define KT   32            // key tile (trimmed for LDS/occupancy)
#define CS   256           // keys per split-K chunk
#define CH   8             // chunks
#define EROWS 160          // E window rows (needs RPB+KT-1 = 159)
#define EPITCH 33          // odd pitch: per-lane b32 reads conflict-free
#define KVP  36            // kt/vt pitch: rows 16B-aligned
#define PW   36            // partial record width (floats): 32 acc + m + l + pad

// ---------------- present: pure relayout ----------------
__global__ void present_copy(const float* __restrict__ x,
                             float* __restrict__ pres) {
    long o = ((long)blockIdx.x * blockDim.x + threadIdx.x) * 4;
    int d0 = (int)(o & 31);
    int s  = (int)((o >> 5) & (SEQ - 1));
    int h  = (int)((o >> 16) & (NH - 1));
    int c  = (int)((o >> 20) & 1);
    int b  = (int)(o >> 21);
    const float4* in = (const float4*)(x + ((long)(b * SEQ + s)) * XROW
                                       + (1 + c) * 512 + h * 32 + d0);
    *((float4*)(pres + o)) = in[0];
}

// ---------------- split-K partial flash ----------------
__global__ __launch_bounds__(RPB)
void attn_partial(const float* __restrict__ x,
                  const float* __restrict__ E,
                  float* __restrict__ ws) {
    __shared__ float kt[KT][KVP];
    __shared__ float vt[KT][KVP];
    __shared__ float et[EROWS][EPITCH];

    int bh = blockIdx.x;               // b*16+h
    int rt = 15 - (int)blockIdx.y;     // heavy row-tiles first
    int c  = blockIdx.z;               // key chunk
    int r0 = rt * RPB;
    if (c * CS > r0 + RPB - 1) return; // whole block inactive (uniform)
    int b  = bh >> 4;
    int h  = bh & 15;
    int tid = threadIdx.x;
    int i  = r0 + tid;

    float q[DHD];
    {
        const float4* q4 = (const float4*)(x + ((long)(b * SEQ + i)) * XROW + h * 32);
#pragma unroll
        for (int t = 0; t < 8; ++t) ((float4*)q)[t] = q4[t];
    }

    float m = -1e30f, l = 0.f;
    float acc[DHD];
#pragma unroll
    for (int d = 0; d < DHD; ++d) acc[d] = 0.f;

    const float* Eh = E + (long)h * SEQ * DHD;

    for (int t0 = 0; t0 < CS / KT; ++t0) {
        int j0 = c * CS + t0 * KT;
        if (j0 > r0 + RPB - 1) break;  // uniform

        // stage K/V: 64 rows x 8 float4 slots = 512, coalesced (8 lanes/row)
#pragma unroll
        for (int t = 0; t < 4; ++t) {
            int s   = t * RPB + tid;       // 0..511
            int row2 = s >> 3;             // 0..63
            int qq  = s & 7;
            int isv = row2 >> 5;
            int r   = row2 & 31;
            float4 g = *(const float4*)(x + ((long)(b * SEQ + j0 + r)) * XROW
                                        + (1 + isv) * 512 + h * 32 + qq * 4);
            float* dst = isv ? &vt[r][qq * 4] : &kt[r][qq * 4];
            *((float4*)dst) = g;
        }
        // stage E window rows eb0..eb0+159 (in-tile row = 127 - tid + jj)
        {
            int eb0 = (SEQ - 1) - (r0 + RPB - 1) + j0;
#pragma unroll
            for (int p = 0; p < 10; ++p) {
                int s  = p * RPB + tid;    // 0..1279
                int r  = s >> 3;
                int qq = s & 7;
                int gr = eb0 + r; if (gr > SEQ - 1) gr = SEQ - 1;  // masked rows only
                float4 g = *(const float4*)(Eh + (long)gr * DHD + qq * 4);
                et[r][qq * 4 + 0] = g.x;
                et[r][qq * 4 + 1] = g.y;
                et[r][qq * 4 + 2] = g.z;
                et[r][qq * 4 + 3] = g.w;
            }
        }
        __syncthreads();

        int jend = i - j0 + 1;             // causal
        if (jend > KT) jend = KT;
        int er0 = RPB - 1 - tid;
        for (int jj = 0; jj < jend; ++jj) {
            const float* ep = &et[er0 + jj][0];
            const float* kp = &kt[jj][0];
            float dk0 = 0.f, dk1 = 0.f, dk2 = 0.f, dk3 = 0.f;
            float de0 = 0.f, de1 = 0.f, de2 = 0.f, de3 = 0.f;
#pragma unroll
            for (int d = 0; d < 8; ++d) {   // 4-way split chains (8-deep each)
                dk0 = __builtin_fmaf(q[d],      kp[d],      dk0);
                dk1 = __builtin_fmaf(q[d + 8],  kp[d + 8],  dk1);
                dk2 = __builtin_fmaf(q[d + 16], kp[d + 16], dk2);
                dk3 = __builtin_fmaf(q[d + 24], kp[d + 24], dk3);
                de0 = __builtin_fmaf(q[d],      ep[d],      de0);
                de1 = __builtin_fmaf(q[d + 8],  ep[d + 8],  de1);
                de2 = __builtin_fmaf(q[d + 16], ep[d + 16], de2);
                de3 = __builtin_fmaf(q[d + 24], ep[d + 24], de3);
            }
            float sc = (((dk0 + dk1) + (dk2 + dk3)) + ((de0 + de1) + (de2 + de3)))
                       * 0.17677669529663687f;

            if (sc > m) {                  // rare rescale
                float r = __expf(m - sc);
                l *= r;
#pragma unroll
                for (int d = 0; d < DHD; ++d) acc[d] *= r;
                m = sc;
            }
            float p = __expf(sc - m);
            l += p;
#pragma unroll
            for (int d = 0; d < DHD; ++d)
                acc[d] = __builtin_fmaf(p, vt[jj][d], acc[d]);
        }
        __syncthreads();
    }

    // write partial record
    float4* w4 = (float4*)(ws + (((long)bh * SEQ + i) * CH + c) * PW);
#pragma unroll
    for (int t = 0; t < 8; ++t) {
        float4 w;
        w.x = acc[t * 4 + 0]; w.y = acc[t * 4 + 1];
        w.z = acc[t * 4 + 2]; w.w = acc[t * 4 + 3];
        w4[t] = w;
    }
    float4 ml; ml.x = m; ml.y = l; ml.z = 0.f; ml.w = 0.f;
    w4[8] = ml;
}

// ---------------- combine partials ----------------
__global__ __launch_bounds__(256)
void attn_combine(const float* __restrict__ ws, float* __restrict__ out) {
    long g = (long)blockIdx.x * 256 + threadIdx.x;   // 0..65535
    int i  = (int)(g & (SEQ - 1));
    int bh = (int)(g >> 11);
    int b  = bh >> 4;
    int h  = bh & 15;
    int cmax = i >> 8;                               // chunks 0..cmax are valid

    const float* base = ws + ((long)bh * SEQ + i) * CH * PW;
    float M = -1e30f;
    for (int c = 0; c <= cmax; ++c) {
        float mm = base[c * PW + 32];
        if (mm > M) M = mm;
    }
    float T = 0.f;
    float acc[DHD];
#pragma unroll
    for (int d = 0; d < DHD; ++d) acc[d] = 0.f;
    for (int c = 0; c <= cmax; ++c) {
        const float4* p4 = (const float4*)(base + c * PW);
        float mm = base[c * PW + 32], ll = base[c * PW + 33];
        float w = __expf(mm - M);
        T += ll * w;
#pragma unroll
        for (int t = 0; t < 8; ++t) {
            float4 v = p4[t];
            acc[t * 4 + 0] = __builtin_fmaf(v.x, w, acc[t * 4 + 0]);
            acc[t * 4 + 1] = __builtin_fmaf(v.y, w, acc[t * 4 + 1]);
            acc[t * 4 + 2] = __builtin_fmaf(v.z, w, acc[t * 4 + 2]);
            acc[t * 4 + 3] = __builtin_fmaf(v.w, w, acc[t * 4 + 3]);
        }
    }
    float inv = 1.0f / T;
    float4* op = (float4*)(out + ((long)(b * SEQ + i)) * 512 + h * 32);
#pragma unroll
    for (int t = 0; t < 8; ++t) {
        float4 w;
        w.x = acc[t * 4 + 0] * inv; w.y = acc[t * 4 + 1] * inv;
        w.z = acc[t * 4 + 2] * inv; w.w = acc[t * 4 + 3] * inv;
        op[t] = w;
    }
}

// ---------------- fallback (round-5 kernel, if ws too small) ----------------
__global__ __launch_bounds__(RPB)
void attn_mono(const float* __restrict__ x, const float* __restrict__ E,
               float* __restrict__ out) {
    __shared__ float kt[64][KVP];
    __shared__ float vt[64][KVP];
    __shared__ float et[192][EPITCH];
    int bh = blockIdx.x & 31;
    int rt = 15 - (blockIdx.x >> 5);
    int b = bh >> 4, h = bh & 15;
    int tid = threadIdx.x;
    int r0 = rt * RPB;
    int i = r0 + tid;
    float q[DHD];
    const float4* q4 = (const float4*)(x + ((long)(b * SEQ + i)) * XROW + h * 32);
#pragma unroll
    for (int t = 0; t < 8; ++t) ((float4*)q)[t] = q4[t];
    float m = -1e30f, l = 0.f;
    float acc[DHD];
#pragma unroll
    for (int d = 0; d < DHD; ++d) acc[d] = 0.f;
    const float* Eh = E + (long)h * SEQ * DHD;
    int ntile = (rt + 1) * 2;
    for (int t0 = 0; t0 < ntile; ++t0) {
        int j0 = t0 * 64;
        {
            int r = tid & 63, isv = tid >> 6;
            const float4* s4 = (const float4*)(x + ((long)(b * SEQ + j0 + r)) * XROW
                                               + (1 + isv) * 512 + h * 32);
            float4 tmp[8];
#pragma unroll
            for (int t = 0; t < 8; ++t) tmp[t] = s4[t];
            float* dst = isv ? &vt[r][0] : &kt[r][0];
#pragma unroll
            for (int t = 0; t < 8; ++t) ((float4*)dst)[t] = tmp[t];
        }
        {
            int eb0 = (SEQ - 1) - (r0 + RPB - 1) + j0;
#pragma unroll
            for (int p = 0; p < 12; ++p) {
                int idx = p * RPB + tid;
                int r = idx >> 3, qq = idx & 7;
                int gr = eb0 + r; if (gr > SEQ - 1) gr = SEQ - 1;
                float4 g = *(const float4*)(Eh + (long)gr * DHD + qq * 4);
                et[r][qq * 4 + 0] = g.x; et[r][qq * 4 + 1] = g.y;
                et[r][qq * 4 + 2] = g.z; et[r][qq * 4 + 3] = g.w;
            }
        }
        __syncthreads();
        int jend = i - j0 + 1; if (jend > 64) jend = 64;
        int er0 = RPB - 1 - tid;
        for (int jj = 0; jj < jend; ++jj) {
            const float* ep = &et[er0 + jj][0];
            float dk = 0.f, de = 0.f;
#pragma unroll
            for (int d = 0; d < DHD; ++d) {
                dk = __builtin_fmaf(q[d], kt[jj][d], dk);
                de = __builtin_fmaf(q[d], ep[d], de);
            }
            float sc = (dk + de) * 0.17677669529663687f;
            if (sc > m) {
                float r = __expf(m - sc);
                l *= r;
#pragma unroll
                for (int d = 0; d < DHD; ++d) acc[d] *= r;
                m = sc;
            }
            float p = __expf(sc - m);
            l += p;
#pragma unroll
            for (int d = 0; d < DHD; ++d)
                acc[d] = __builtin_fmaf(p, vt[jj][d], acc[d]);
        }
        __syncthreads();
    }
    float inv = 1.0f / l;
    float* op = out + ((long)(b * SEQ + i)) * 512 + h * 32;
#pragma unroll
    for (int t = 0; t < 8; ++t) {
        float4 w;
        w.x = acc[t*4+0]*inv; w.y = acc[t*4+1]*inv;
        w.z = acc[t*4+2]*inv; w.w = acc[t*4+3]*inv;
        ((float4*)op)[t] = w;
    }
}

extern "C" void kernel_launch(void* const* d_in, const int* in_sizes, int n_in,
                              void* d_out, int out_size, void* d_ws, size_t ws_size,
                              hipStream_t stream) {
    const float* x = (const float*)d_in[0];
    const float* E = (const float*)d_in[1];
    if (n_in >= 2 && in_sizes[0] == 1048576) { const float* t = x; x = E; E = t; }
    float* a    = (float*)d_out;
    float* pres = a + (long)NB * SEQ * NH * DHD;

    const size_t WS_NEED = (size_t)NB * NH * SEQ * CH * PW * sizeof(float); // 75.5 MB
    if (ws_size >= WS_NEED) {
        attn_partial<<<dim3(32, 16, CH), dim3(RPB), 0, stream>>>(x, E, (float*)d_ws);
        attn_combine<<<dim3(65536 / 256), dim3(256), 0, stream>>>((const float*)d_ws, a);
    } else {
        attn_mono<<<dim3(32 * 16), dim3(RPB), 0, stream>>>(x, E, a);
    }
    present_copy<<<dim3(4096), dim3(256), 0, stream>>>(x, pres);
}

// Round 7
// 212.653 us; speedup vs baseline: 9.0298x; 2.5840x over previous
//
#include <hip/hip_runtime.h>
#include <hip/hip_bf16.h>

#define NH   16
#define DHD  32
#define SEQ  2048
#define NB   2
#define XROW 1536
#define PP   96            // P-tile row pitch (bf16 units): b128 reads 2-way only

typedef unsigned short u16;
typedef __attribute__((ext_vector_type(8))) short bf16x8;
typedef __attribute__((ext_vector_type(4))) float f32x4;

static __device__ __forceinline__ u16 f2b(float f) {
    __hip_bfloat16 h = __float2bfloat16(f);   // RNE
    return *(u16*)&h;
}

// ---------- prepass: Q,K -> bf16 [bh][s][d] ----------
__global__ void prep_qk(const float* __restrict__ x,
                        u16* __restrict__ Qb, u16* __restrict__ Kb) {
    long o = ((long)blockIdx.x * 256 + threadIdx.x) * 8;   // over 4M elems
    int d = (int)(o & 31);
    int s = (int)((o >> 5) & (SEQ - 1));
    int h = (int)((o >> 16) & 15);
    int c = (int)((o >> 20) & 1);
    int b = (int)(o >> 21);
    const float4* src = (const float4*)(x + ((long)(b * SEQ + s)) * XROW
                                        + c * 512 + h * 32 + d);
    float4 f0 = src[0], f1 = src[1];
    u16 pk[8];
    pk[0]=f2b(f0.x); pk[1]=f2b(f0.y); pk[2]=f2b(f0.z); pk[3]=f2b(f0.w);
    pk[4]=f2b(f1.x); pk[5]=f2b(f1.y); pk[6]=f2b(f1.z); pk[7]=f2b(f1.w);
    u16* dst = (c ? Kb : Qb) + ((long)((b * NH + h) * SEQ + s)) * 32 + d;
    *(uint4*)dst = *(uint4*)pk;
}

// ---------- prepass: E -> bf16 [h][m][d] ----------
__global__ void prep_e(const float* __restrict__ E, u16* __restrict__ Eb) {
    long o = ((long)blockIdx.x * 256 + threadIdx.x) * 8;   // over 1M elems
    const float4* src = (const float4*)(E + o);
    float4 f0 = src[0], f1 = src[1];
    u16 pk[8];
    pk[0]=f2b(f0.x); pk[1]=f2b(f0.y); pk[2]=f2b(f0.z); pk[3]=f2b(f0.w);
    pk[4]=f2b(f1.x); pk[5]=f2b(f1.y); pk[6]=f2b(f1.z); pk[7]=f2b(f1.w);
    *(uint4*)(Eb + o) = *(uint4*)pk;
}

// ---------- prepass: V -> bf16 transposed [bh][d][s] ----------
__global__ __launch_bounds__(256)
void prep_vt(const float* __restrict__ x, u16* __restrict__ Vt) {
    __shared__ float t[64][33];
    int bh = blockIdx.x & 31;
    int s0 = (blockIdx.x >> 5) << 6;
    int b = bh >> 4, h = bh & 15;
    int tid = threadIdx.x;
    int sr = tid >> 3, d4 = (tid & 7) * 4;
    const float* base = x + (long)b * SEQ * XROW + 1024 + h * 32;
    float4 f = *(const float4*)(base + (long)(s0 + sr) * XROW + d4);
    t[sr][d4] = f.x; t[sr][d4+1] = f.y; t[sr][d4+2] = f.z; t[sr][d4+3] = f.w;
    f = *(const float4*)(base + (long)(s0 + sr + 32) * XROW + d4);
    t[sr+32][d4] = f.x; t[sr+32][d4+1] = f.y; t[sr+32][d4+2] = f.z; t[sr+32][d4+3] = f.w;
    __syncthreads();
    int d = tid >> 3, sg = (tid & 7) * 8;
    u16 pk[8];
#pragma unroll
    for (int k = 0; k < 8; ++k) pk[k] = f2b(t[sg + k][d]);
    *(uint4*)(Vt + ((long)(bh * 32 + d)) * SEQ + s0 + sg) = *(uint4*)pk;
}

// ---------- MFMA flash attention ----------
__global__ __launch_bounds__(256, 4)
void attn_mfma(const u16* __restrict__ Qb, const u16* __restrict__ Kb,
               const u16* __restrict__ Vt, const u16* __restrict__ Eb,
               float* __restrict__ out) {
    __shared__ u16 pls[4][16 * PP];     // per-wave private P tile

    int gslot = blockIdx.x & 31;
    int bh    = blockIdx.x >> 5;
    int g = (gslot & 1) ? (31 - (gslot >> 1)) : (gslot >> 1);  // heavy/light pairing
    int b = bh >> 4, h = bh & 15;
    int wv   = threadIdx.x >> 6;
    int lane = threadIdx.x & 63;
    int n16  = lane & 15;
    int quad = lane >> 4;
    int i0 = g * 64 + wv * 16;

    const u16* Kbh = Kb + (long)bh * SEQ * 32;
    const u16* Vbh = Vt + (long)bh * 32 * SEQ;
    const u16* Ebh = Eb + (long)h * SEQ * 32;

    bf16x8 qf = *(const bf16x8*)(Qb + ((long)bh * SEQ + i0 + n16) * 32 + quad * 8);

    f32x4 O0 = {0.f,0.f,0.f,0.f}, O1 = {0.f,0.f,0.f,0.f};
    float m[4] = {-1e30f,-1e30f,-1e30f,-1e30f};
    float l[4] = {0.f,0.f,0.f,0.f};
    const f32x4 zero = {0.f,0.f,0.f,0.f};
    const float scale = 0.17677669529663687f;

    u16* pw = &pls[wv][0];
    int cbase = 15 - quad * 4 + n16;          // skew col index for reg 0
    int permhi = (lane & 48) << 2;            // bpermute addr high bits

    int nch = (i0 >> 6) + 1;
    for (int ch = 0; ch < nch; ++ch) {
        int j0c = ch << 6;
        int mw0 = 2032 - i0 + j0c;            // E window base (never negative)

        // rolling rel products P0,P1 over E-window frags t=0..4
        f32x4 P0, P1;
        {
            int row = mw0 + n16; if (row > SEQ - 1) row = SEQ - 1;
            bf16x8 ef = *(const bf16x8*)(Ebh + (long)row * 32 + quad * 8);
            P0 = __builtin_amdgcn_mfma_f32_16x16x32_bf16(qf, ef, zero, 0, 0, 0);
        }
        f32x4 w[4];
#pragma unroll
        for (int s = 0; s < 4; ++s) {
            {
                int row = mw0 + 16 * (s + 1) + n16; if (row > SEQ - 1) row = SEQ - 1;
                bf16x8 ef = *(const bf16x8*)(Ebh + (long)row * 32 + quad * 8);
                P1 = __builtin_amdgcn_mfma_f32_16x16x32_bf16(qf, ef, zero, 0, 0, 0);
            }
            f32x4 C;
            {
                bf16x8 kf = *(const bf16x8*)(Kbh + (long)(j0c + 16*s + n16) * 32 + quad * 8);
                C = __builtin_amdgcn_mfma_f32_16x16x32_bf16(qf, kf, zero, 0, 0, 0);
            }
#pragma unroll
            for (int r = 0; r < 4; ++r) {     // skew-select rel, combine, scale
                int c = cbase - r;
                int addr = permhi | ((c & 15) << 2);
                int v0 = __builtin_amdgcn_ds_bpermute(addr, __float_as_int(P0[r]));
                int v1 = __builtin_amdgcn_ds_bpermute(addr, __float_as_int(P1[r]));
                float rel = (c < 16) ? __int_as_float(v0) : __int_as_float(v1);
                w[s][r] = (C[r] + rel) * scale;
            }
            P0 = P1;
        }

        if (ch == nch - 1) {                  // causal mask (diagonal chunk only)
            int jb = j0c + n16 - i0;          // j - i0 at s=0
#pragma unroll
            for (int s = 0; s < 4; ++s)
#pragma unroll
                for (int r = 0; r < 4; ++r)
                    if (jb + 16 * s > quad * 4 + r) w[s][r] = -1e30f;
        }

        // online softmax: row stats (row = quad*4+r, 16 lanes/row-group)
        float al[4];
#pragma unroll
        for (int r = 0; r < 4; ++r) {
            float t = fmaxf(fmaxf(w[0][r], w[1][r]), fmaxf(w[2][r], w[3][r]));
            t = fmaxf(t, __shfl_xor(t, 1));
            t = fmaxf(t, __shfl_xor(t, 2));
            t = fmaxf(t, __shfl_xor(t, 4));
            t = fmaxf(t, __shfl_xor(t, 8));
            float mn = fmaxf(m[r], t);
            al[r] = __expf(m[r] - mn);
            m[r] = mn;
        }
#pragma unroll
        for (int s = 0; s < 4; ++s)
#pragma unroll
            for (int r = 0; r < 4; ++r)
                w[s][r] = __expf(w[s][r] - m[r]);   // p (masked -> 0)
#pragma unroll
        for (int r = 0; r < 4; ++r) {
            float rs = (w[0][r] + w[1][r]) + (w[2][r] + w[3][r]);
            rs += __shfl_xor(rs, 1);
            rs += __shfl_xor(rs, 2);
            rs += __shfl_xor(rs, 4);
            rs += __shfl_xor(rs, 8);
            l[r] = l[r] * al[r] + rs;
            O0[r] *= al[r];
            O1[r] *= al[r];
        }

        // P -> LDS (C-layout write), re-read as A-frags
#pragma unroll
        for (int s = 0; s < 4; ++s)
#pragma unroll
            for (int r = 0; r < 4; ++r)
                pw[(quad * 4 + r) * PP + 16 * s + n16] = f2b(w[s][r]);

        bf16x8 pa0 = *(const bf16x8*)(pw + n16 * PP + quad * 8);
        bf16x8 pa1 = *(const bf16x8*)(pw + n16 * PP + 32 + quad * 8);

        bf16x8 v00 = *(const bf16x8*)(Vbh + (long)n16 * SEQ        + j0c      + quad * 8);
        bf16x8 v01 = *(const bf16x8*)(Vbh + (long)n16 * SEQ        + j0c + 32 + quad * 8);
        bf16x8 v10 = *(const bf16x8*)(Vbh + (long)(16 + n16) * SEQ + j0c      + quad * 8);
        bf16x8 v11 = *(const bf16x8*)(Vbh + (long)(16 + n16) * SEQ + j0c + 32 + quad * 8);

        O0 = __builtin_amdgcn_mfma_f32_16x16x32_bf16(pa0, v00, O0, 0, 0, 0);
        O0 = __builtin_amdgcn_mfma_f32_16x16x32_bf16(pa1, v01, O0, 0, 0, 0);
        O1 = __builtin_amdgcn_mfma_f32_16x16x32_bf16(pa0, v10, O1, 0, 0, 0);
        O1 = __builtin_amdgcn_mfma_f32_16x16x32_bf16(pa1, v11, O1, 0, 0, 0);
    }

    float* ob = out + ((long)b * SEQ + i0) * 512 + h * 32;
#pragma unroll
    for (int r = 0; r < 4; ++r) {
        float inv = 1.0f / l[r];
        ob[(quad * 4 + r) * 512 + n16]      = O0[r] * inv;
        ob[(quad * 4 + r) * 512 + 16 + n16] = O1[r] * inv;
    }
}

// ---------- present: pure relayout ----------
__global__ void present_copy(const float* __restrict__ x,
                             float* __restrict__ pres) {
    long o = ((long)blockIdx.x * blockDim.x + threadIdx.x) * 4;
    int d0 = (int)(o & 31);
    int s  = (int)((o >> 5) & (SEQ - 1));
    int h  = (int)((o >> 16) & (NH - 1));
    int c  = (int)((o >> 20) & 1);
    int b  = (int)(o >> 21);
    const float4* in = (const float4*)(x + ((long)(b * SEQ + s)) * XROW
                                       + (1 + c) * 512 + h * 32 + d0);
    *((float4*)(pres + o)) = in[0];
}

// ---------- fallback (round-5 kernel, if ws too small) ----------
__global__ __launch_bounds__(128)
void attn_mono(const float* __restrict__ x, const float* __restrict__ E,
               float* __restrict__ out) {
    __shared__ float kt[64][36];
    __shared__ float vt[64][36];
    __shared__ float et[192][33];
    int bh = blockIdx.x & 31;
    int rt = 15 - (blockIdx.x >> 5);
    int b = bh >> 4, h = bh & 15;
    int tid = threadIdx.x;
    int r0 = rt * 128;
    int i = r0 + tid;
    float q[DHD];
    const float4* q4 = (const float4*)(x + ((long)(b * SEQ + i)) * XROW + h * 32);
#pragma unroll
    for (int t = 0; t < 8; ++t) ((float4*)q)[t] = q4[t];
    float m = -1e30f, l = 0.f;
    float acc[DHD];
#pragma unroll
    for (int d = 0; d < DHD; ++d) acc[d] = 0.f;
    const float* Eh = E + (long)h * SEQ * DHD;
    int ntile = (rt + 1) * 2;
    for (int t0 = 0; t0 < ntile; ++t0) {
        int j0 = t0 * 64;
        {
            int r = tid & 63, isv = tid >> 6;
            const float4* s4 = (const float4*)(x + ((long)(b * SEQ + j0 + r)) * XROW
                                               + (1 + isv) * 512 + h * 32);
            float4 tmp[8];
#pragma unroll
            for (int t = 0; t < 8; ++t) tmp[t] = s4[t];
            float* dst = isv ? &vt[r][0] : &kt[r][0];
#pragma unroll
            for (int t = 0; t < 8; ++t) ((float4*)dst)[t] = tmp[t];
        }
        {
            int eb0 = (SEQ - 1) - (r0 + 127) + j0;
#pragma unroll
            for (int p = 0; p < 12; ++p) {
                int idx = p * 128 + tid;
                int r = idx >> 3, qq = idx & 7;
                int gr = eb0 + r; if (gr > SEQ - 1) gr = SEQ - 1;
                float4 gg = *(const float4*)(Eh + (long)gr * DHD + qq * 4);
                et[r][qq*4+0] = gg.x; et[r][qq*4+1] = gg.y;
                et[r][qq*4+2] = gg.z; et[r][qq*4+3] = gg.w;
            }
        }
        __syncthreads();
        int jend = i - j0 + 1; if (jend > 64) jend = 64;
        int er0 = 127 - tid;
        for (int jj = 0; jj < jend; ++jj) {
            const float* ep = &et[er0 + jj][0];
            float dk = 0.f, de = 0.f;
#pragma unroll
            for (int d = 0; d < DHD; ++d) {
                dk = __builtin_fmaf(q[d], kt[jj][d], dk);
                de = __builtin_fmaf(q[d], ep[d], de);
            }
            float sc = (dk + de) * 0.17677669529663687f;
            if (sc > m) {
                float r = __expf(m - sc);
                l *= r;
#pragma unroll
                for (int d = 0; d < DHD; ++d) acc[d] *= r;
                m = sc;
            }
            float p = __expf(sc - m);
            l += p;
#pragma unroll
            for (int d = 0; d < DHD; ++d)
                acc[d] = __builtin_fmaf(p, vt[jj][d], acc[d]);
        }
        __syncthreads();
    }
    float inv = 1.0f / l;
    float* op = out + ((long)(b * SEQ + i)) * 512 + h * 32;
#pragma unroll
    for (int t = 0; t < 8; ++t) {
        float4 w;
        w.x = acc[t*4+0]*inv; w.y = acc[t*4+1]*inv;
        w.z = acc[t*4+2]*inv; w.w = acc[t*4+3]*inv;
        ((float4*)op)[t] = w;
    }
}

extern "C" void kernel_launch(void* const* d_in, const int* in_sizes, int n_in,
                              void* d_out, int out_size, void* d_ws, size_t ws_size,
                              hipStream_t stream) {
    const float* x = (const float*)d_in[0];
    const float* E = (const float*)d_in[1];
    if (n_in >= 2 && in_sizes[0] == 1048576) { const float* t = x; x = E; E = t; }
    float* a    = (float*)d_out;
    float* pres = a + (long)NB * SEQ * NH * DHD;

    const long QK = (long)NB * NH * SEQ * 32;          // 2,097,152 elems each
    const size_t WS_NEED = (size_t)(3 * QK + NH * SEQ * 32) * sizeof(u16);  // ~14.7 MB
    if (ws_size >= WS_NEED) {
        u16* Qb = (u16*)d_ws;
        u16* Kb = Qb + QK;
        u16* Vt = Kb + QK;
        u16* Eb = Vt + QK;
        prep_qk<<<dim3(2048), dim3(256), 0, stream>>>(x, Qb, Kb);
        prep_vt<<<dim3(1024), dim3(256), 0, stream>>>(x, Vt);
        prep_e <<<dim3(512),  dim3(256), 0, stream>>>(E, Eb);
        attn_mfma<<<dim3(1024), dim3(256), 0, stream>>>(Qb, Kb, Vt, Eb, a);
    } else {
        attn_mono<<<dim3(512), dim3(128), 0, stream>>>(x, E, a);
    }
    present_copy<<<dim3(4096), dim3(256), 0, stream>>>(x, pres);
}

// Round 9
// 204.921 us; speedup vs baseline: 9.3705x; 1.0377x over previous
//
#include <hip/hip_runtime.h>
#include <hip/hip_bf16.h>

#define NH   16
#define DHD  32
#define SEQ  2048
#define NB   2
#define XROW 1536
#define PP   72   // P-tile pitch (u16). MUST be >=64 (row width). 144B rows: 16B-aligned,
                  // 4*144 % 128 = 64 -> odd quads shift 16 banks -> 4-way write conflicts.

typedef unsigned short u16;
typedef __attribute__((ext_vector_type(8))) short bf16x8;
typedef __attribute__((ext_vector_type(4))) float f32x4;

static __device__ __forceinline__ u16 f2b(float f) {
    __hip_bfloat16 h = __float2bfloat16(f);   // RNE
    return *(u16*)&h;
}

// ---------- fused prep: K,E -> bf16, V -> bf16 transposed, present copy ----------
__global__ __launch_bounds__(256)
void prep_all(const float* __restrict__ x, const float* __restrict__ E,
              u16* __restrict__ Kb, u16* __restrict__ Vt, u16* __restrict__ Eb,
              float* __restrict__ pres) {
    __shared__ float t[64][33];
    int bid = blockIdx.x;
    int tid = threadIdx.x;
    if (bid < 1024) {                 // K -> bf16 [bh][s][d]
        long o = ((long)bid * 256 + tid) * 8;
        int d = (int)(o & 31);
        int s = (int)((o >> 5) & (SEQ - 1));
        int bh = (int)(o >> 16);
        int b = bh >> 4, h = bh & 15;
        const float* src = x + ((long)(b * SEQ + s)) * XROW + 512 + h * 32 + d;
        float4 f0 = *(const float4*)src, f1 = *(const float4*)(src + 4);
        u16 pk[8] = {f2b(f0.x), f2b(f0.y), f2b(f0.z), f2b(f0.w),
                     f2b(f1.x), f2b(f1.y), f2b(f1.z), f2b(f1.w)};
        *(uint4*)(Kb + o) = *(uint4*)pk;
    } else if (bid < 1536) {          // E -> bf16 dense [h][m][d]
        long o = ((long)(bid - 1024) * 256 + tid) * 8;
        const float* src = E + o;
        float4 f0 = *(const float4*)src, f1 = *(const float4*)(src + 4);
        u16 pk[8] = {f2b(f0.x), f2b(f0.y), f2b(f0.z), f2b(f0.w),
                     f2b(f1.x), f2b(f1.y), f2b(f1.z), f2b(f1.w)};
        *(uint4*)(Eb + o) = *(uint4*)pk;
    } else if (bid < 2560) {          // V -> bf16 transposed [bh][d][s]
        int vb = bid - 1536;
        int bh = vb & 31;
        int s0 = (vb >> 5) << 6;
        int b = bh >> 4, h = bh & 15;
        int sr = tid >> 3, d4 = (tid & 7) * 4;
        const float* base = x + (long)b * SEQ * XROW + 1024 + h * 32;
        float4 f = *(const float4*)(base + (long)(s0 + sr) * XROW + d4);
        t[sr][d4] = f.x; t[sr][d4+1] = f.y; t[sr][d4+2] = f.z; t[sr][d4+3] = f.w;
        f = *(const float4*)(base + (long)(s0 + sr + 32) * XROW + d4);
        t[sr+32][d4] = f.x; t[sr+32][d4+1] = f.y; t[sr+32][d4+2] = f.z; t[sr+32][d4+3] = f.w;
        __syncthreads();
        int d = tid >> 3, sg = (tid & 7) * 8;
        u16 pk[8];
#pragma unroll
        for (int k = 0; k < 8; ++k) pk[k] = f2b(t[sg + k][d]);
        *(uint4*)(Vt + ((long)(bh * 32 + d)) * SEQ + s0 + sg) = *(uint4*)pk;
    } else {                          // present fp32 relayout
        long o = ((long)(bid - 2560) * 256 + tid) * 4;
        int d0 = (int)(o & 31);
        int s  = (int)((o >> 5) & (SEQ - 1));
        int h  = (int)((o >> 16) & (NH - 1));
        int c  = (int)((o >> 20) & 1);
        int b  = (int)(o >> 21);
        const float4* in = (const float4*)(x + ((long)(b * SEQ + s)) * XROW
                                           + (1 + c) * 512 + h * 32 + d0);
        *((float4*)(pres + o)) = in[0];
    }
}

// ---------- MFMA flash attention, fixed-max softmax, MFMA row-sums ----------
__global__ __launch_bounds__(128, 4)
void attn_mfma(const float* __restrict__ x, const u16* __restrict__ Kb,
               const u16* __restrict__ Vt, const u16* __restrict__ Eb,
               float* __restrict__ out) {
    __shared__ u16 pls[2][16 * PP];

    int gslot = blockIdx.x & 63;
    int bh    = blockIdx.x >> 6;
    int g = (gslot & 1) ? (63 - (gslot >> 1)) : (gslot >> 1);  // heavy/light pairing
    int b = bh >> 4, h = bh & 15;
    int wv   = threadIdx.x >> 6;
    int lane = threadIdx.x & 63;
    int n16  = lane & 15;
    int quad = lane >> 4;
    int i0 = g * 32 + wv * 16;

    const u16* Kbh = Kb + (long)bh * SEQ * 32;
    const u16* Vbh = Vt + (long)bh * 32 * SEQ;
    const u16* Ebh = Eb + (long)h * SEQ * 32;

    // Q frag from x fp32, scale folded in (so scores need no post-multiply)
    const float scale = 0.17677669529663687f;   // rsqrt(32)
    bf16x8 qf;
    {
        const float* qp = x + ((long)(b * SEQ) + i0 + n16) * XROW + h * 32 + quad * 8;
        float4 f0 = *(const float4*)qp, f1 = *(const float4*)(qp + 4);
        u16 pk[8] = {f2b(f0.x*scale), f2b(f0.y*scale), f2b(f0.z*scale), f2b(f0.w*scale),
                     f2b(f1.x*scale), f2b(f1.y*scale), f2b(f1.z*scale), f2b(f1.w*scale)};
        qf = *(bf16x8*)pk;
    }

    bf16x8 ones;
#pragma unroll
    for (int k = 0; k < 8; ++k) ones[k] = (short)0x3F80;   // bf16 1.0

    f32x4 O0 = {0.f,0.f,0.f,0.f}, O1 = {0.f,0.f,0.f,0.f}, Os = {0.f,0.f,0.f,0.f};
    const f32x4 zero = {0.f,0.f,0.f,0.f};

    u16* pw = &pls[wv][0];
    int cbase = 15 - quad * 4 + n16;          // skew col index for reg 0 (s-invariant)
    int permhi = (lane & 48) << 2;

    int nch = (i0 >> 6) + 1;
    for (int ch = 0; ch < nch; ++ch) {
        int j0c = ch << 6;
        int mw0 = 2032 - i0 + j0c;            // E window base (>= 0)

        f32x4 P0, P1;
        {
            int row = mw0 + n16; if (row > SEQ - 1) row = SEQ - 1;
            bf16x8 ef = *(const bf16x8*)(Ebh + (long)row * 32 + quad * 8);
            P0 = __builtin_amdgcn_mfma_f32_16x16x32_bf16(qf, ef, zero, 0, 0, 0);
        }
        f32x4 w[4];
#pragma unroll
        for (int s = 0; s < 4; ++s) {
            {
                int row = mw0 + 16 * (s + 1) + n16; if (row > SEQ - 1) row = SEQ - 1;
                bf16x8 ef = *(const bf16x8*)(Ebh + (long)row * 32 + quad * 8);
                P1 = __builtin_amdgcn_mfma_f32_16x16x32_bf16(qf, ef, zero, 0, 0, 0);
            }
            f32x4 C;
            {
                bf16x8 kf = *(const bf16x8*)(Kbh + (long)(j0c + 16*s + n16) * 32 + quad * 8);
                C = __builtin_amdgcn_mfma_f32_16x16x32_bf16(qf, kf, zero, 0, 0, 0);
            }
#pragma unroll
            for (int r = 0; r < 4; ++r) {     // skew-select rel (addresses s-invariant)
                int c = cbase - r;
                int addr = permhi | ((c & 15) << 2);
                int v0 = __builtin_amdgcn_ds_bpermute(addr, __float_as_int(P0[r]));
                int v1 = __builtin_amdgcn_ds_bpermute(addr, __float_as_int(P1[r]));
                float rel = (c < 16) ? __int_as_float(v0) : __int_as_float(v1);
                w[s][r] = C[r] + rel;          // already scaled via qf
            }
            P0 = P1;
        }

        if (ch == nch - 1) {                  // causal mask (diagonal chunk only)
            int jb = j0c + n16 - i0;
#pragma unroll
            for (int s = 0; s < 4; ++s)
#pragma unroll
                for (int r = 0; r < 4; ++r)
                    if (jb + 16 * s > quad * 4 + r) w[s][r] = -1e30f;
        }

        // fixed-max softmax: p = exp(sc); masked -> 0
#pragma unroll
        for (int s = 0; s < 4; ++s)
#pragma unroll
            for (int r = 0; r < 4; ++r)
                w[s][r] = __expf(w[s][r]);

        // P -> LDS (C-layout write), re-read as A-frags
#pragma unroll
        for (int s = 0; s < 4; ++s)
#pragma unroll
            for (int r = 0; r < 4; ++r)
                pw[(quad * 4 + r) * PP + 16 * s + n16] = f2b(w[s][r]);

        bf16x8 pa0 = *(const bf16x8*)(pw + n16 * PP + quad * 8);
        bf16x8 pa1 = *(const bf16x8*)(pw + n16 * PP + 32 + quad * 8);

        bf16x8 v00 = *(const bf16x8*)(Vbh + (long)n16 * SEQ        + j0c      + quad * 8);
        bf16x8 v01 = *(const bf16x8*)(Vbh + (long)n16 * SEQ        + j0c + 32 + quad * 8);
        bf16x8 v10 = *(const bf16x8*)(Vbh + (long)(16 + n16) * SEQ + j0c      + quad * 8);
        bf16x8 v11 = *(const bf16x8*)(Vbh + (long)(16 + n16) * SEQ + j0c + 32 + quad * 8);

        O0 = __builtin_amdgcn_mfma_f32_16x16x32_bf16(pa0, v00, O0, 0, 0, 0);
        O0 = __builtin_amdgcn_mfma_f32_16x16x32_bf16(pa1, v01, O0, 0, 0, 0);
        O1 = __builtin_amdgcn_mfma_f32_16x16x32_bf16(pa0, v10, O1, 0, 0, 0);
        O1 = __builtin_amdgcn_mfma_f32_16x16x32_bf16(pa1, v11, O1, 0, 0, 0);
        Os = __builtin_amdgcn_mfma_f32_16x16x32_bf16(pa0, ones, Os, 0, 0, 0);
        Os = __builtin_amdgcn_mfma_f32_16x16x32_bf16(pa1, ones, Os, 0, 0, 0);
    }

    float* ob = out + ((long)b * SEQ + i0) * 512 + h * 32;
#pragma unroll
    for (int r = 0; r < 4; ++r) {
        float inv = 1.0f / Os[r];              // l[r]: all 16 cols of Os identical
        ob[(quad * 4 + r) * 512 + n16]      = O0[r] * inv;
        ob[(quad * 4 + r) * 512 + 16 + n16] = O1[r] * inv;
    }
}

// ---------- fallback path (ws too small): round-5 scalar flash + present ----------
__global__ void present_copy(const float* __restrict__ x, float* __restrict__ pres) {
    long o = ((long)blockIdx.x * blockDim.x + threadIdx.x) * 4;
    int d0 = (int)(o & 31);
    int s  = (int)((o >> 5) & (SEQ - 1));
    int h  = (int)((o >> 16) & (NH - 1));
    int c  = (int)((o >> 20) & 1);
    int b  = (int)(o >> 21);
    const float4* in = (const float4*)(x + ((long)(b * SEQ + s)) * XROW
                                       + (1 + c) * 512 + h * 32 + d0);
    *((float4*)(pres + o)) = in[0];
}

__global__ __launch_bounds__(128)
void attn_mono(const float* __restrict__ x, const float* __restrict__ E,
               float* __restrict__ out) {
    __shared__ float kt[64][36];
    __shared__ float vt[64][36];
    __shared__ float et[192][33];
    int bh = blockIdx.x & 31;
    int rt = 15 - (blockIdx.x >> 5);
    int b = bh >> 4, h = bh & 15;
    int tid = threadIdx.x;
    int r0 = rt * 128;
    int i = r0 + tid;
    float q[DHD];
    const float4* q4 = (const float4*)(x + ((long)(b * SEQ + i)) * XROW + h * 32);
#pragma unroll
    for (int t = 0; t < 8; ++t) ((float4*)q)[t] = q4[t];
    float m = -1e30f, l = 0.f;
    float acc[DHD];
#pragma unroll
    for (int d = 0; d < DHD; ++d) acc[d] = 0.f;
    const float* Eh = E + (long)h * SEQ * DHD;
    int ntile = (rt + 1) * 2;
    for (int t0 = 0; t0 < ntile; ++t0) {
        int j0 = t0 * 64;
        {
            int r = tid & 63, isv = tid >> 6;
            const float4* s4 = (const float4*)(x + ((long)(b * SEQ + j0 + r)) * XROW
                                               + (1 + isv) * 512 + h * 32);
            float4 tmp[8];
#pragma unroll
            for (int t = 0; t < 8; ++t) tmp[t] = s4[t];
            float* dst = isv ? &vt[r][0] : &kt[r][0];
#pragma unroll
            for (int t = 0; t < 8; ++t) ((float4*)dst)[t] = tmp[t];
        }
        {
            int eb0 = (SEQ - 1) - (r0 + 127) + j0;
#pragma unroll
            for (int p = 0; p < 12; ++p) {
                int idx = p * 128 + tid;
                int r = idx >> 3, qq = idx & 7;
                int gr = eb0 + r; if (gr > SEQ - 1) gr = SEQ - 1;
                float4 gg = *(const float4*)(Eh + (long)gr * DHD + qq * 4);
                et[r][qq*4+0] = gg.x; et[r][qq*4+1] = gg.y;
                et[r][qq*4+2] = gg.z; et[r][qq*4+3] = gg.w;
            }
        }
        __syncthreads();
        int jend = i - j0 + 1; if (jend > 64) jend = 64;
        int er0 = 127 - tid;
        for (int jj = 0; jj < jend; ++jj) {
            const float* ep = &et[er0 + jj][0];
            float dk = 0.f, de = 0.f;
#pragma unroll
            for (int d = 0; d < DHD; ++d) {
                dk = __builtin_fmaf(q[d], kt[jj][d], dk);
                de = __builtin_fmaf(q[d], ep[d], de);
            }
            float sc = (dk + de) * 0.17677669529663687f;
            if (sc > m) {
                float r = __expf(m - sc);
                l *= r;
#pragma unroll
                for (int d = 0; d < DHD; ++d) acc[d] *= r;
                m = sc;
            }
            float p = __expf(sc - m);
            l += p;
#pragma unroll
            for (int d = 0; d < DHD; ++d)
                acc[d] = __builtin_fmaf(p, vt[jj][d], acc[d]);
        }
        __syncthreads();
    }
    float inv = 1.0f / l;
    float* op = out + ((long)(b * SEQ + i)) * 512 + h * 32;
#pragma unroll
    for (int t = 0; t < 8; ++t) {
        float4 w;
        w.x = acc[t*4+0]*inv; w.y = acc[t*4+1]*inv;
        w.z = acc[t*4+2]*inv; w.w = acc[t*4+3]*inv;
        ((float4*)op)[t] = w;
    }
}

extern "C" void kernel_launch(void* const* d_in, const int* in_sizes, int n_in,
                              void* d_out, int out_size, void* d_ws, size_t ws_size,
                              hipStream_t stream) {
    const float* x = (const float*)d_in[0];
    const float* E = (const float*)d_in[1];
    if (n_in >= 2 && in_sizes[0] == 1048576) { const float* t = x; x = E; E = t; }
    float* a    = (float*)d_out;
    float* pres = a + (long)NB * SEQ * NH * DHD;

    const long KN = (long)NB * NH * SEQ * 32;            // 2,097,152
    const long EN = (long)NH * SEQ * 32;                 // 1,048,576
    const size_t WS_NEED = (size_t)(2 * KN + EN) * sizeof(u16);   // ~10.5 MB
    if (ws_size >= WS_NEED) {
        u16* Kb = (u16*)d_ws;
        u16* Vt = Kb + KN;
        u16* Eb = Vt + KN;
        prep_all<<<dim3(6656), dim3(256), 0, stream>>>(x, E, Kb, Vt, Eb, pres);
        attn_mfma<<<dim3(2048), dim3(128), 0, stream>>>(x, Kb, Vt, Eb, a);
    } else {
        attn_mono<<<dim3(512), dim3(128), 0, stream>>>(x, E, a);
        present_copy<<<dim3(4096), dim3(256), 0, stream>>>(x, pres);
    }
}

// Round 10
// 154.813 us; speedup vs baseline: 12.4035x; 1.3237x over previous
//
#include <hip/hip_runtime.h>
#include <hip/hip_bf16.h>

#define NH   16
#define DHD  32
#define SEQ  2048
#define NB   2
#define XROW 1536
#define PP   72   // P-tile pitch (u16), >=64. 144B rows: 16B-aligned, 4-way write conflicts.

typedef unsigned short u16;
typedef __attribute__((ext_vector_type(8))) short bf16x8;
typedef __attribute__((ext_vector_type(4))) float f32x4;

static __device__ __forceinline__ u16 f2b(float f) {
    __hip_bfloat16 h = __float2bfloat16(f);   // RNE
    return *(u16*)&h;
}

// ---------- fused prep: K,E -> bf16, V -> bf16 transposed, present copy ----------
__global__ __launch_bounds__(256)
void prep_all(const float* __restrict__ x, const float* __restrict__ E,
              u16* __restrict__ Kb, u16* __restrict__ Vt, u16* __restrict__ Eb,
              float* __restrict__ pres) {
    __shared__ float t[64][33];
    int bid = blockIdx.x;
    int tid = threadIdx.x;
    if (bid < 1024) {                 // K -> bf16 [bh][s][d]
        long o = ((long)bid * 256 + tid) * 8;
        int d = (int)(o & 31);
        int s = (int)((o >> 5) & (SEQ - 1));
        int bh = (int)(o >> 16);
        int b = bh >> 4, h = bh & 15;
        const float* src = x + ((long)(b * SEQ + s)) * XROW + 512 + h * 32 + d;
        float4 f0 = *(const float4*)src, f1 = *(const float4*)(src + 4);
        u16 pk[8] = {f2b(f0.x), f2b(f0.y), f2b(f0.z), f2b(f0.w),
                     f2b(f1.x), f2b(f1.y), f2b(f1.z), f2b(f1.w)};
        *(uint4*)(Kb + o) = *(uint4*)pk;
    } else if (bid < 1536) {          // E -> bf16 dense [h][m][d]
        long o = ((long)(bid - 1024) * 256 + tid) * 8;
        const float* src = E + o;
        float4 f0 = *(const float4*)src, f1 = *(const float4*)(src + 4);
        u16 pk[8] = {f2b(f0.x), f2b(f0.y), f2b(f0.z), f2b(f0.w),
                     f2b(f1.x), f2b(f1.y), f2b(f1.z), f2b(f1.w)};
        *(uint4*)(Eb + o) = *(uint4*)pk;
    } else if (bid < 2560) {          // V -> bf16 transposed [bh][d][s]
        int vb = bid - 1536;
        int bh = vb & 31;
        int s0 = (vb >> 5) << 6;
        int b = bh >> 4, h = bh & 15;
        int sr = tid >> 3, d4 = (tid & 7) * 4;
        const float* base = x + (long)b * SEQ * XROW + 1024 + h * 32;
        float4 f = *(const float4*)(base + (long)(s0 + sr) * XROW + d4);
        t[sr][d4] = f.x; t[sr][d4+1] = f.y; t[sr][d4+2] = f.z; t[sr][d4+3] = f.w;
        f = *(const float4*)(base + (long)(s0 + sr + 32) * XROW + d4);
        t[sr+32][d4] = f.x; t[sr+32][d4+1] = f.y; t[sr+32][d4+2] = f.z; t[sr+32][d4+3] = f.w;
        __syncthreads();
        int d = tid >> 3, sg = (tid & 7) * 8;
        u16 pk[8];
#pragma unroll
        for (int k = 0; k < 8; ++k) pk[k] = f2b(t[sg + k][d]);
        *(uint4*)(Vt + ((long)(bh * 32 + d)) * SEQ + s0 + sg) = *(uint4*)pk;
    } else {                          // present fp32 relayout
        long o = ((long)(bid - 2560) * 256 + tid) * 4;
        int d0 = (int)(o & 31);
        int s  = (int)((o >> 5) & (SEQ - 1));
        int h  = (int)((o >> 16) & (NH - 1));
        int c  = (int)((o >> 20) & 1);
        int b  = (int)(o >> 21);
        const float4* in = (const float4*)(x + ((long)(b * SEQ + s)) * XROW
                                           + (1 + c) * 512 + h * 32 + d0);
        *((float4*)(pres + o)) = in[0];
    }
}

// ---------- MFMA flash attention: 4 waves split-K one 16-row tile, add-combine ----------
__global__ __launch_bounds__(256, 8)
void attn_mfma(const float* __restrict__ x, const u16* __restrict__ Kb,
               const u16* __restrict__ Vt, const u16* __restrict__ Eb,
               float* __restrict__ out) {
    __shared__ u16  pls[4][16 * PP];
    __shared__ float comb[4][16][33];   // cols 0..31 = O, col 32 = l

    int bh = blockIdx.x & 31;
    int gt = 127 - (blockIdx.x >> 5);   // heavy tiles dispatched first
    int b = bh >> 4, h = bh & 15;
    int wv   = threadIdx.x >> 6;
    int lane = threadIdx.x & 63;
    int n16  = lane & 15;
    int quad = lane >> 4;
    int i0 = gt * 16;

    const u16* Kbh = Kb + (long)bh * SEQ * 32;
    const u16* Vbh = Vt + (long)bh * 32 * SEQ;
    const u16* Ebh = Eb + (long)h * SEQ * 32;

    // Q frag from x fp32, scale folded in
    const float scale = 0.17677669529663687f;   // rsqrt(32)
    bf16x8 qf;
    {
        const float* qp = x + ((long)(b * SEQ) + i0 + n16) * XROW + h * 32 + quad * 8;
        float4 f0 = *(const float4*)qp, f1 = *(const float4*)(qp + 4);
        u16 pk[8] = {f2b(f0.x*scale), f2b(f0.y*scale), f2b(f0.z*scale), f2b(f0.w*scale),
                     f2b(f1.x*scale), f2b(f1.y*scale), f2b(f1.z*scale), f2b(f1.w*scale)};
        qf = *(bf16x8*)pk;
    }

    bf16x8 ones;
#pragma unroll
    for (int k = 0; k < 8; ++k) ones[k] = (short)0x3F80;   // bf16 1.0

    f32x4 O0 = {0.f,0.f,0.f,0.f}, O1 = {0.f,0.f,0.f,0.f}, Os = {0.f,0.f,0.f,0.f};
    const f32x4 zero = {0.f,0.f,0.f,0.f};

    u16* pw = &pls[wv][0];
    int cbase = 15 - quad * 4 + n16;
    int permhi = (lane & 48) << 2;

    int nch = (i0 >> 6) + 1;
    for (int ch = wv; ch < nch; ch += 4) {   // split-K across the block's 4 waves
        int j0c = ch << 6;
        int mw0 = 2032 - i0 + j0c;           // E window base (>= 0)

        f32x4 P0, P1;
        {
            int row = mw0 + n16; if (row > SEQ - 1) row = SEQ - 1;
            bf16x8 ef = *(const bf16x8*)(Ebh + (long)row * 32 + quad * 8);
            P0 = __builtin_amdgcn_mfma_f32_16x16x32_bf16(qf, ef, zero, 0, 0, 0);
        }
        f32x4 w[4];
#pragma unroll
        for (int s = 0; s < 4; ++s) {
            {
                int row = mw0 + 16 * (s + 1) + n16; if (row > SEQ - 1) row = SEQ - 1;
                bf16x8 ef = *(const bf16x8*)(Ebh + (long)row * 32 + quad * 8);
                P1 = __builtin_amdgcn_mfma_f32_16x16x32_bf16(qf, ef, zero, 0, 0, 0);
            }
            f32x4 C;
            {
                bf16x8 kf = *(const bf16x8*)(Kbh + (long)(j0c + 16*s + n16) * 32 + quad * 8);
                C = __builtin_amdgcn_mfma_f32_16x16x32_bf16(qf, kf, zero, 0, 0, 0);
            }
#pragma unroll
            for (int r = 0; r < 4; ++r) {    // skew-select rel
                int c = cbase - r;
                int addr = permhi | ((c & 15) << 2);
                int v0 = __builtin_amdgcn_ds_bpermute(addr, __float_as_int(P0[r]));
                int v1 = __builtin_amdgcn_ds_bpermute(addr, __float_as_int(P1[r]));
                float rel = (c < 16) ? __int_as_float(v0) : __int_as_float(v1);
                w[s][r] = C[r] + rel;
            }
            P0 = P1;
        }

        if (ch == nch - 1) {                 // causal mask (diagonal chunk only)
            int jb = j0c + n16 - i0;
#pragma unroll
            for (int s = 0; s < 4; ++s)
#pragma unroll
                for (int r = 0; r < 4; ++r)
                    if (jb + 16 * s > quad * 4 + r) w[s][r] = -1e30f;
        }

#pragma unroll
        for (int s = 0; s < 4; ++s)
#pragma unroll
            for (int r = 0; r < 4; ++r)
                w[s][r] = __expf(w[s][r]);   // fixed-max softmax; masked -> 0

        // P -> LDS (C-layout), re-read as A-frags (per-wave private, no barrier)
#pragma unroll
        for (int s = 0; s < 4; ++s)
#pragma unroll
            for (int r = 0; r < 4; ++r)
                pw[(quad * 4 + r) * PP + 16 * s + n16] = f2b(w[s][r]);

        bf16x8 pa0 = *(const bf16x8*)(pw + n16 * PP + quad * 8);
        bf16x8 pa1 = *(const bf16x8*)(pw + n16 * PP + 32 + quad * 8);

        bf16x8 v00 = *(const bf16x8*)(Vbh + (long)n16 * SEQ        + j0c      + quad * 8);
        bf16x8 v01 = *(const bf16x8*)(Vbh + (long)n16 * SEQ        + j0c + 32 + quad * 8);
        bf16x8 v10 = *(const bf16x8*)(Vbh + (long)(16 + n16) * SEQ + j0c      + quad * 8);
        bf16x8 v11 = *(const bf16x8*)(Vbh + (long)(16 + n16) * SEQ + j0c + 32 + quad * 8);

        O0 = __builtin_amdgcn_mfma_f32_16x16x32_bf16(pa0, v00, O0, 0, 0, 0);
        O0 = __builtin_amdgcn_mfma_f32_16x16x32_bf16(pa1, v01, O0, 0, 0, 0);
        O1 = __builtin_amdgcn_mfma_f32_16x16x32_bf16(pa0, v10, O1, 0, 0, 0);
        O1 = __builtin_amdgcn_mfma_f32_16x16x32_bf16(pa1, v11, O1, 0, 0, 0);
        Os = __builtin_amdgcn_mfma_f32_16x16x32_bf16(pa0, ones, Os, 0, 0, 0);
        Os = __builtin_amdgcn_mfma_f32_16x16x32_bf16(pa1, ones, Os, 0, 0, 0);
    }

    // per-wave partials -> LDS (fixed-max partials are exactly additive)
#pragma unroll
    for (int r = 0; r < 4; ++r) {
        comb[wv][quad * 4 + r][n16]      = O0[r];
        comb[wv][quad * 4 + r][16 + n16] = O1[r];
        if (n16 == 0) comb[wv][quad * 4 + r][32] = Os[r];
    }
    __syncthreads();

    int row = threadIdx.x >> 4;          // 0..15
    int c2  = (threadIdx.x & 15) * 2;    // 0,2,..,30
    float s0 = 0.f, s1 = 0.f, ls = 0.f;
#pragma unroll
    for (int v = 0; v < 4; ++v) {
        s0 += comb[v][row][c2];
        s1 += comb[v][row][c2 + 1];
        ls += comb[v][row][32];
    }
    float inv = 1.0f / ls;
    float* op = out + ((long)(b * SEQ) + i0 + row) * 512 + h * 32 + c2;
    op[0] = s0 * inv;
    op[1] = s1 * inv;
}

// ---------- fallback path (ws too small): scalar flash + present ----------
__global__ void present_copy(const float* __restrict__ x, float* __restrict__ pres) {
    long o = ((long)blockIdx.x * blockDim.x + threadIdx.x) * 4;
    int d0 = (int)(o & 31);
    int s  = (int)((o >> 5) & (SEQ - 1));
    int h  = (int)((o >> 16) & (NH - 1));
    int c  = (int)((o >> 20) & 1);
    int b  = (int)(o >> 21);
    const float4* in = (const float4*)(x + ((long)(b * SEQ + s)) * XROW
                                       + (1 + c) * 512 + h * 32 + d0);
    *((float4*)(pres + o)) = in[0];
}

__global__ __launch_bounds__(128)
void attn_mono(const float* __restrict__ x, const float* __restrict__ E,
               float* __restrict__ out) {
    __shared__ float kt[64][36];
    __shared__ float vt[64][36];
    __shared__ float et[192][33];
    int bh = blockIdx.x & 31;
    int rt = 15 - (blockIdx.x >> 5);
    int b = bh >> 4, h = bh & 15;
    int tid = threadIdx.x;
    int r0 = rt * 128;
    int i = r0 + tid;
    float q[DHD];
    const float4* q4 = (const float4*)(x + ((long)(b * SEQ + i)) * XROW + h * 32);
#pragma unroll
    for (int t = 0; t < 8; ++t) ((float4*)q)[t] = q4[t];
    float m = -1e30f, l = 0.f;
    float acc[DHD];
#pragma unroll
    for (int d = 0; d < DHD; ++d) acc[d] = 0.f;
    const float* Eh = E + (long)h * SEQ * DHD;
    int ntile = (rt + 1) * 2;
    for (int t0 = 0; t0 < ntile; ++t0) {
        int j0 = t0 * 64;
        {
            int r = tid & 63, isv = tid >> 6;
            const float4* s4 = (const float4*)(x + ((long)(b * SEQ + j0 + r)) * XROW
                                               + (1 + isv) * 512 + h * 32);
            float4 tmp[8];
#pragma unroll
            for (int t = 0; t < 8; ++t) tmp[t] = s4[t];
            float* dst = isv ? &vt[r][0] : &kt[r][0];
#pragma unroll
            for (int t = 0; t < 8; ++t) ((float4*)dst)[t] = tmp[t];
        }
        {
            int eb0 = (SEQ - 1) - (r0 + 127) + j0;
#pragma unroll
            for (int p = 0; p < 12; ++p) {
                int idx = p * 128 + tid;
                int r = idx >> 3, qq = idx & 7;
                int gr = eb0 + r; if (gr > SEQ - 1) gr = SEQ - 1;
                float4 gg = *(const float4*)(Eh + (long)gr * DHD + qq * 4);
                et[r][qq*4+0] = gg.x; et[r][qq*4+1] = gg.y;
                et[r][qq*4+2] = gg.z; et[r][qq*4+3] = gg.w;
            }
        }
        __syncthreads();
        int jend = i - j0 + 1; if (jend > 64) jend = 64;
        int er0 = 127 - tid;
        for (int jj = 0; jj < jend; ++jj) {
            const float* ep = &et[er0 + jj][0];
            float dk = 0.f, de = 0.f;
#pragma unroll
            for (int d = 0; d < DHD; ++d) {
                dk = __builtin_fmaf(q[d], kt[jj][d], dk);
                de = __builtin_fmaf(q[d], ep[d], de);
            }
            float sc = (dk + de) * 0.17677669529663687f;
            if (sc > m) {
                float r = __expf(m - sc);
                l *= r;
#pragma unroll
                for (int d = 0; d < DHD; ++d) acc[d] *= r;
                m = sc;
            }
            float p = __expf(sc - m);
            l += p;
#pragma unroll
            for (int d = 0; d < DHD; ++d)
                acc[d] = __builtin_fmaf(p, vt[jj][d], acc[d]);
        }
        __syncthreads();
    }
    float inv = 1.0f / l;
    float* op = out + ((long)(b * SEQ + i)) * 512 + h * 32;
#pragma unroll
    for (int t = 0; t < 8; ++t) {
        float4 w;
        w.x = acc[t*4+0]*inv; w.y = acc[t*4+1]*inv;
        w.z = acc[t*4+2]*inv; w.w = acc[t*4+3]*inv;
        ((float4*)op)[t] = w;
    }
}

extern "C" void kernel_launch(void* const* d_in, const int* in_sizes, int n_in,
                              void* d_out, int out_size, void* d_ws, size_t ws_size,
                              hipStream_t stream) {
    const float* x = (const float*)d_in[0];
    const float* E = (const float*)d_in[1];
    if (n_in >= 2 && in_sizes[0] == 1048576) { const float* t = x; x = E; E = t; }
    float* a    = (float*)d_out;
    float* pres = a + (long)NB * SEQ * NH * DHD;

    const long KN = (long)NB * NH * SEQ * 32;            // 2,097,152
    const long EN = (long)NH * SEQ * 32;                 // 1,048,576
    const size_t WS_NEED = (size_t)(2 * KN + EN) * sizeof(u16);   // ~10.5 MB
    if (ws_size >= WS_NEED) {
        u16* Kb = (u16*)d_ws;
        u16* Vt = Kb + KN;
        u16* Eb = Vt + KN;
        prep_all<<<dim3(6656), dim3(256), 0, stream>>>(x, E, Kb, Vt, Eb, pres);
        attn_mfma<<<dim3(4096), dim3(256), 0, stream>>>(x, Kb, Vt, Eb, a);
    } else {
        attn_mono<<<dim3(512), dim3(128), 0, stream>>>(x, E, a);
        present_copy<<<dim3(4096), dim3(256), 0, stream>>>(x, pres);
    }
}

// Round 11
// 149.652 us; speedup vs baseline: 12.8312x; 1.0345x over previous
//
#include <hip/hip_runtime.h>
#include <hip/hip_bf16.h>

#define NH   16
#define DHD  32
#define SEQ  2048
#define NB   2
#define XROW 1536
#define PP   72   // P-tile pitch (u16), >=64. 144B rows: 16B-aligned, 4-way write conflicts.

typedef unsigned short u16;
typedef __attribute__((ext_vector_type(8))) short bf16x8;
typedef __attribute__((ext_vector_type(4))) float f32x4;

static __device__ __forceinline__ u16 f2b(float f) {
    __hip_bfloat16 h = __float2bfloat16(f);   // RNE
    return *(u16*)&h;
}

// ---------- prep: K,E -> bf16, V -> bf16 transposed ----------
__global__ __launch_bounds__(256)
void prep_all(const float* __restrict__ x, const float* __restrict__ E,
              u16* __restrict__ Kb, u16* __restrict__ Vt, u16* __restrict__ Eb) {
    __shared__ float t[64][33];
    int bid = blockIdx.x;
    int tid = threadIdx.x;
    if (bid < 1024) {                 // K -> bf16 [bh][s][d]
        long o = ((long)bid * 256 + tid) * 8;
        int d = (int)(o & 31);
        int s = (int)((o >> 5) & (SEQ - 1));
        int bh = (int)(o >> 16);
        int b = bh >> 4, h = bh & 15;
        const float* src = x + ((long)(b * SEQ + s)) * XROW + 512 + h * 32 + d;
        float4 f0 = *(const float4*)src, f1 = *(const float4*)(src + 4);
        u16 pk[8] = {f2b(f0.x), f2b(f0.y), f2b(f0.z), f2b(f0.w),
                     f2b(f1.x), f2b(f1.y), f2b(f1.z), f2b(f1.w)};
        *(uint4*)(Kb + o) = *(uint4*)pk;
    } else if (bid < 1536) {          // E -> bf16 dense [h][m][d]
        long o = ((long)(bid - 1024) * 256 + tid) * 8;
        const float* src = E + o;
        float4 f0 = *(const float4*)src, f1 = *(const float4*)(src + 4);
        u16 pk[8] = {f2b(f0.x), f2b(f0.y), f2b(f0.z), f2b(f0.w),
                     f2b(f1.x), f2b(f1.y), f2b(f1.z), f2b(f1.w)};
        *(uint4*)(Eb + o) = *(uint4*)pk;
    } else {                          // V -> bf16 transposed [bh][d][s]
        int vb = bid - 1536;
        int bh = vb & 31;
        int s0 = (vb >> 5) << 6;
        int b = bh >> 4, h = bh & 15;
        int sr = tid >> 3, d4 = (tid & 7) * 4;
        const float* base = x + (long)b * SEQ * XROW + 1024 + h * 32;
        float4 f = *(const float4*)(base + (long)(s0 + sr) * XROW + d4);
        t[sr][d4] = f.x; t[sr][d4+1] = f.y; t[sr][d4+2] = f.z; t[sr][d4+3] = f.w;
        f = *(const float4*)(base + (long)(s0 + sr + 32) * XROW + d4);
        t[sr+32][d4] = f.x; t[sr+32][d4+1] = f.y; t[sr+32][d4+2] = f.z; t[sr+32][d4+3] = f.w;
        __syncthreads();
        int d = tid >> 3, sg = (tid & 7) * 8;
        u16 pk[8];
#pragma unroll
        for (int k = 0; k < 8; ++k) pk[k] = f2b(t[sg + k][d]);
        *(uint4*)(Vt + ((long)(bh * 32 + d)) * SEQ + s0 + sg) = *(uint4*)pk;
    }
}

// ---------- MFMA flash attention + fused present tail ----------
__global__ __launch_bounds__(256, 8)
void attn_mfma(const float* __restrict__ x, const u16* __restrict__ Kb,
               const u16* __restrict__ Vt, const u16* __restrict__ Eb,
               float* __restrict__ out, float* __restrict__ pres) {
    __shared__ u16  pls[4][16 * PP];
    __shared__ float comb[4][16][33];   // cols 0..31 = O, col 32 = l

    int bh = blockIdx.x & 31;
    int gt = 127 - (blockIdx.x >> 5);   // heavy tiles dispatched first
    int b = bh >> 4, h = bh & 15;
    int wv   = threadIdx.x >> 6;
    int lane = threadIdx.x & 63;
    int n16  = lane & 15;
    int quad = lane >> 4;
    int i0 = gt * 16;

    const u16* Kbh = Kb + (long)bh * SEQ * 32;
    const u16* Vbh = Vt + (long)bh * 32 * SEQ;
    const u16* Ebh = Eb + (long)h * SEQ * 32;

    // Q frag from x fp32, scale folded in
    const float scale = 0.17677669529663687f;   // rsqrt(32)
    bf16x8 qf;
    {
        const float* qp = x + ((long)(b * SEQ) + i0 + n16) * XROW + h * 32 + quad * 8;
        float4 f0 = *(const float4*)qp, f1 = *(const float4*)(qp + 4);
        u16 pk[8] = {f2b(f0.x*scale), f2b(f0.y*scale), f2b(f0.z*scale), f2b(f0.w*scale),
                     f2b(f1.x*scale), f2b(f1.y*scale), f2b(f1.z*scale), f2b(f1.w*scale)};
        qf = *(bf16x8*)pk;
    }

    bf16x8 ones;
#pragma unroll
    for (int k = 0; k < 8; ++k) ones[k] = (short)0x3F80;   // bf16 1.0

    f32x4 O0 = {0.f,0.f,0.f,0.f}, O1 = {0.f,0.f,0.f,0.f}, Os = {0.f,0.f,0.f,0.f};
    const f32x4 zero = {0.f,0.f,0.f,0.f};

    u16* pw = &pls[wv][0];
    int cbase = 15 - quad * 4 + n16;
    int permhi = (lane & 48) << 2;

    int nch = (i0 >> 6) + 1;
    for (int ch = wv; ch < nch; ch += 4) {   // split-K across the block's 4 waves
        int j0c = ch << 6;
        int mw0 = 2032 - i0 + j0c;           // E window base (>= 0)

        f32x4 P0, P1;
        float rel0[4];
        {
            int row = mw0 + n16; if (row > SEQ - 1) row = SEQ - 1;
            bf16x8 ef = *(const bf16x8*)(Ebh + (long)row * 32 + quad * 8);
            P0 = __builtin_amdgcn_mfma_f32_16x16x32_bf16(qf, ef, zero, 0, 0, 0);
        }
#pragma unroll
        for (int r = 0; r < 4; ++r) {        // permuted frag-0 values
            int addr = permhi | (((cbase - r) & 15) << 2);
            rel0[r] = __int_as_float(
                __builtin_amdgcn_ds_bpermute(addr, __float_as_int(P0[r])));
        }
        f32x4 w[4];
#pragma unroll
        for (int s = 0; s < 4; ++s) {
            {
                int row = mw0 + 16 * (s + 1) + n16; if (row > SEQ - 1) row = SEQ - 1;
                bf16x8 ef = *(const bf16x8*)(Ebh + (long)row * 32 + quad * 8);
                P1 = __builtin_amdgcn_mfma_f32_16x16x32_bf16(qf, ef, zero, 0, 0, 0);
            }
            f32x4 C;
            {
                bf16x8 kf = *(const bf16x8*)(Kbh + (long)(j0c + 16*s + n16) * 32 + quad * 8);
                C = __builtin_amdgcn_mfma_f32_16x16x32_bf16(qf, kf, zero, 0, 0, 0);
            }
#pragma unroll
            for (int r = 0; r < 4; ++r) {    // skew-select rel; reuse prev permute
                int c = cbase - r;
                int addr = permhi | ((c & 15) << 2);
                float rel1 = __int_as_float(
                    __builtin_amdgcn_ds_bpermute(addr, __float_as_int(P1[r])));
                float rel = (c < 16) ? rel0[r] : rel1;
                w[s][r] = C[r] + rel;
                rel0[r] = rel1;              // frag s+1 becomes "low" frag next step
            }
            P0 = P1;
        }

        if (ch == nch - 1) {                 // causal mask (diagonal chunk only)
            int jb = j0c + n16 - i0;
#pragma unroll
            for (int s = 0; s < 4; ++s)
#pragma unroll
                for (int r = 0; r < 4; ++r)
                    if (jb + 16 * s > quad * 4 + r) w[s][r] = -1e30f;
        }

#pragma unroll
        for (int s = 0; s < 4; ++s)
#pragma unroll
            for (int r = 0; r < 4; ++r)
                w[s][r] = __expf(w[s][r]);   // fixed-max softmax; masked -> 0

        // P -> LDS (C-layout), re-read as A-frags (per-wave private, no barrier)
#pragma unroll
        for (int s = 0; s < 4; ++s)
#pragma unroll
            for (int r = 0; r < 4; ++r)
                pw[(quad * 4 + r) * PP + 16 * s + n16] = f2b(w[s][r]);

        bf16x8 pa0 = *(const bf16x8*)(pw + n16 * PP + quad * 8);
        bf16x8 pa1 = *(const bf16x8*)(pw + n16 * PP + 32 + quad * 8);

        bf16x8 v00 = *(const bf16x8*)(Vbh + (long)n16 * SEQ        + j0c      + quad * 8);
        bf16x8 v01 = *(const bf16x8*)(Vbh + (long)n16 * SEQ        + j0c + 32 + quad * 8);
        bf16x8 v10 = *(const bf16x8*)(Vbh + (long)(16 + n16) * SEQ + j0c      + quad * 8);
        bf16x8 v11 = *(const bf16x8*)(Vbh + (long)(16 + n16) * SEQ + j0c + 32 + quad * 8);

        O0 = __builtin_amdgcn_mfma_f32_16x16x32_bf16(pa0, v00, O0, 0, 0, 0);
        O0 = __builtin_amdgcn_mfma_f32_16x16x32_bf16(pa1, v01, O0, 0, 0, 0);
        O1 = __builtin_amdgcn_mfma_f32_16x16x32_bf16(pa0, v10, O1, 0, 0, 0);
        O1 = __builtin_amdgcn_mfma_f32_16x16x32_bf16(pa1, v11, O1, 0, 0, 0);
        Os = __builtin_amdgcn_mfma_f32_16x16x32_bf16(pa0, ones, Os, 0, 0, 0);
        Os = __builtin_amdgcn_mfma_f32_16x16x32_bf16(pa1, ones, Os, 0, 0, 0);
    }

    // per-wave partials -> LDS (fixed-max partials are exactly additive)
#pragma unroll
    for (int r = 0; r < 4; ++r) {
        comb[wv][quad * 4 + r][n16]      = O0[r];
        comb[wv][quad * 4 + r][16 + n16] = O1[r];
        if (n16 == 0) comb[wv][quad * 4 + r][32] = Os[r];
    }
    __syncthreads();

    int row = threadIdx.x >> 4;          // 0..15
    int c2  = (threadIdx.x & 15) * 2;    // 0,2,..,30
    float s0 = 0.f, s1 = 0.f, ls = 0.f;
#pragma unroll
    for (int v = 0; v < 4; ++v) {
        s0 += comb[v][row][c2];
        s1 += comb[v][row][c2 + 1];
        ls += comb[v][row][32];
    }
    float inv = 1.0f / ls;
    float* op = out + ((long)(b * SEQ) + i0 + row) * 512 + h * 32 + c2;
    op[0] = s0 * inv;
    op[1] = s1 * inv;

    // ---- fused present tail: this block's slice of the [B,2,H,S,D] relayout ----
    {
        long o = ((long)blockIdx.x * 256 + threadIdx.x) * 4;   // 4096*256*4 = 4,194,304
        int d0 = (int)(o & 31);
        int s  = (int)((o >> 5) & (SEQ - 1));
        int hh = (int)((o >> 16) & (NH - 1));
        int cc = (int)((o >> 20) & 1);
        int bb = (int)(o >> 21);
        const float4* in = (const float4*)(x + ((long)(bb * SEQ + s)) * XROW
                                           + (1 + cc) * 512 + hh * 32 + d0);
        *((float4*)(pres + o)) = in[0];
    }
}

// ---------- fallback path (ws too small): scalar flash + present ----------
__global__ void present_copy(const float* __restrict__ x, float* __restrict__ pres) {
    long o = ((long)blockIdx.x * blockDim.x + threadIdx.x) * 4;
    int d0 = (int)(o & 31);
    int s  = (int)((o >> 5) & (SEQ - 1));
    int h  = (int)((o >> 16) & (NH - 1));
    int c  = (int)((o >> 20) & 1);
    int b  = (int)(o >> 21);
    const float4* in = (const float4*)(x + ((long)(b * SEQ + s)) * XROW
                                       + (1 + c) * 512 + h * 32 + d0);
    *((float4*)(pres + o)) = in[0];
}

__global__ __launch_bounds__(128)
void attn_mono(const float* __restrict__ x, const float* __restrict__ E,
               float* __restrict__ out) {
    __shared__ float kt[64][36];
    __shared__ float vt[64][36];
    __shared__ float et[192][33];
    int bh = blockIdx.x & 31;
    int rt = 15 - (blockIdx.x >> 5);
    int b = bh >> 4, h = bh & 15;
    int tid = threadIdx.x;
    int r0 = rt * 128;
    int i = r0 + tid;
    float q[DHD];
    const float4* q4 = (const float4*)(x + ((long)(b * SEQ + i)) * XROW + h * 32);
#pragma unroll
    for (int t = 0; t < 8; ++t) ((float4*)q)[t] = q4[t];
    float m = -1e30f, l = 0.f;
    float acc[DHD];
#pragma unroll
    for (int d = 0; d < DHD; ++d) acc[d] = 0.f;
    const float* Eh = E + (long)h * SEQ * DHD;
    int ntile = (rt + 1) * 2;
    for (int t0 = 0; t0 < ntile; ++t0) {
        int j0 = t0 * 64;
        {
            int r = tid & 63, isv = tid >> 6;
            const float4* s4 = (const float4*)(x + ((long)(b * SEQ + j0 + r)) * XROW
                                               + (1 + isv) * 512 + h * 32);
            float4 tmp[8];
#pragma unroll
            for (int t = 0; t < 8; ++t) tmp[t] = s4[t];
            float* dst = isv ? &vt[r][0] : &kt[r][0];
#pragma unroll
            for (int t = 0; t < 8; ++t) ((float4*)dst)[t] = tmp[t];
        }
        {
            int eb0 = (SEQ - 1) - (r0 + 127) + j0;
#pragma unroll
            for (int p = 0; p < 12; ++p) {
                int idx = p * 128 + tid;
                int r = idx >> 3, qq = idx & 7;
                int gr = eb0 + r; if (gr > SEQ - 1) gr = SEQ - 1;
                float4 gg = *(const float4*)(Eh + (long)gr * DHD + qq * 4);
                et[r][qq*4+0] = gg.x; et[r][qq*4+1] = gg.y;
                et[r][qq*4+2] = gg.z; et[r][qq*4+3] = gg.w;
            }
        }
        __syncthreads();
        int jend = i - j0 + 1; if (jend > 64) jend = 64;
        int er0 = 127 - tid;
        for (int jj = 0; jj < jend; ++jj) {
            const float* ep = &et[er0 + jj][0];
            float dk = 0.f, de = 0.f;
#pragma unroll
            for (int d = 0; d < DHD; ++d) {
                dk = __builtin_fmaf(q[d], kt[jj][d], dk);
                de = __builtin_fmaf(q[d], ep[d], de);
            }
            float sc = (dk + de) * 0.17677669529663687f;
            if (sc > m) {
                float r = __expf(m - sc);
                l *= r;
#pragma unroll
                for (int d = 0; d < DHD; ++d) acc[d] *= r;
                m = sc;
            }
            float p = __expf(sc - m);
            l += p;
#pragma unroll
            for (int d = 0; d < DHD; ++d)
                acc[d] = __builtin_fmaf(p, vt[jj][d], acc[d]);
        }
        __syncthreads();
    }
    float inv = 1.0f / l;
    float* op = out + ((long)(b * SEQ + i)) * 512 + h * 32;
#pragma unroll
    for (int t = 0; t < 8; ++t) {
        float4 w;
        w.x = acc[t*4+0]*inv; w.y = acc[t*4+1]*inv;
        w.z = acc[t*4+2]*inv; w.w = acc[t*4+3]*inv;
        ((float4*)op)[t] = w;
    }
}

extern "C" void kernel_launch(void* const* d_in, const int* in_sizes, int n_in,
                              void* d_out, int out_size, void* d_ws, size_t ws_size,
                              hipStream_t stream) {
    const float* x = (const float*)d_in[0];
    const float* E = (const float*)d_in[1];
    if (n_in >= 2 && in_sizes[0] == 1048576) { const float* t = x; x = E; E = t; }
    float* a    = (float*)d_out;
    float* pres = a + (long)NB * SEQ * NH * DHD;

    const long KN = (long)NB * NH * SEQ * 32;            // 2,097,152
    const long EN = (long)NH * SEQ * 32;                 // 1,048,576
    const size_t WS_NEED = (size_t)(2 * KN + EN) * sizeof(u16);   // ~10.5 MB
    if (ws_size >= WS_NEED) {
        u16* Kb = (u16*)d_ws;
        u16* Vt = Kb + KN;
        u16* Eb = Vt + KN;
        prep_all<<<dim3(2560), dim3(256), 0, stream>>>(x, E, Kb, Vt, Eb);
        attn_mfma<<<dim3(4096), dim3(256), 0, stream>>>(x, Kb, Vt, Eb, a, pres);
    } else {
        attn_mono<<<dim3(512), dim3(128), 0, stream>>>(x, E, a);
        present_copy<<<dim3(4096), dim3(256), 0, stream>>>(x, pres);
    }
}